// Round 2
// baseline (1610.470 us; speedup 1.0000x reference)
//
#include <hip/hip_runtime.h>

// EPN_flax, round 11: round-10 MFMA fold, fixed for q's dynamic range.
// Round-10 failure: q reaches ~1e5 > f16 max (65504); casting a_j=[h,q] to f16
// saturated the q feature -> output destroyed. Fix: aH carries h only (O(1),
// f16-safe); q_j enters via two spare k-slots of the e-term MFMA, widened from
// K=16 to K=32: slot(qd0,j4) = f16(q/16) x W0row (RTN), slot(qd0,j5) =
// residual (q - 16*f16(q/16), |.|<=32) x W0row/16. Reconstructs q*W0row/16 to
// ~1e-4 rel. Eu/Ev get separate e-term A-frags (word2 differs: W0[63] vs
// W0[31]). Everything else as round 10: barrier-free main loop, j-side h-part
// via K=32 MFMA with C-init = Pi (ij) / Qi (ji), both carrying b0; pk-relu;
// per-i register accumulation across j-steps (atomics /4).

constexpr int Nn = 1024;

typedef _Float16 half8 __attribute__((ext_vector_type(8)));
typedef __fp16   fp16x2 __attribute__((ext_vector_type(2)));
typedef float    f32x4 __attribute__((ext_vector_type(4)));
typedef unsigned int uint4v __attribute__((ext_vector_type(4)));

#define MFMAH32(A, B, C) __builtin_amdgcn_mfma_f32_16x16x32_f16(A, B, C, 0, 0, 0)

__device__ inline unsigned int pkrtz(float a, float b) {
    fp16x2 r = __builtin_amdgcn_cvt_pkrtz(a, b);
    return __builtin_bit_cast(unsigned int, r);
}
__device__ inline f32x4 max0(f32x4 a) {
    f32x4 z = {0.f, 0.f, 0.f, 0.f};
    return __builtin_elementwise_max(a, z);
}
// relu on a packed f16 pair (v_pk_max_f16); pkrtz(neg) stays <=0 so
// relu-after-pack == pack-after-relu.
__device__ inline unsigned int relu_pk(unsigned int u) {
    fp16x2 h = __builtin_bit_cast(fp16x2, u);
    fp16x2 z = {(__fp16)0.f, (__fp16)0.f};
    h = __builtin_elementwise_max(h, z);
    return __builtin_bit_cast(unsigned int, h);
}
__device__ inline unsigned int pk_rtn(float lo, float hi) {
    unsigned short l = __builtin_bit_cast(unsigned short, (_Float16)lo);
    unsigned short h = __builtin_bit_cast(unsigned short, (_Float16)hi);
    return ((unsigned int)h << 16) | (unsigned int)l;
}

// ---- setup: weight fragments (3 timesteps), scaled b1/W2, q->qout copy ----
__global__ __launch_bounds__(256) void epn_frag_kernel(
    const float* __restrict__ W0,   // [3][80][64]
    const float* __restrict__ W1,   // [3][64][64]
    const float* __restrict__ b1,   // [3][64]
    const float* __restrict__ W2,   // [3][64]
    const float* __restrict__ qin,
    uint4* __restrict__ aeU,        // [3][4][64]  K=32 e-term A-frags, ij dir
    uint4* __restrict__ aeV,        // [3][4][64]  K=32 e-term A-frags, ji dir
    uint4* __restrict__ fw0a,       // [3][4][64]  K=32 A-frags (W0 rows 0..31, /16)
    uint4* __restrict__ fw0b,       // [3][4][64]  K=32 A-frags (W0 rows 32..63, /16)
    uint4* __restrict__ fw1,        // [3][8][64]  sigma-permuted K=32 A-frags
    float* __restrict__ b1s,        // [3][64] = b1/16
    float* __restrict__ w2s,        // [3][64] = 16*W2
    float* __restrict__ qout)
{
    const int idx = blockIdx.x * 256 + threadIdx.x;   // grid 20 -> 5120
    if (idx < 1536) {                                 // aeU / aeV
        int isV = idx >= 768;
        int i2 = isV ? idx - 768 : idx;
        int lane = i2 & 63, t = (i2 >> 6) & 3, ts = i2 >> 8;
        int nl = lane & 15, qd = lane >> 4;
        float v[4];
        #pragma unroll
        for (int j = 0; j < 4; ++j)
            v[j] = W0[ts * 80 * 64 + (64 + qd * 4 + j) * 64 + t * 16 + nl] * 0.0625f;
        unsigned int w2w = 0u;
        if (qd == 0) {   // q hi/lo slots: elem4 = W0row (for f16(q/16)), elem5 = W0row/16
            float wq = W0[ts * 80 * 64 + (isV ? 31 : 63) * 64 + t * 16 + nl];
            w2w = pk_rtn(wq, wq * 0.0625f);
        }
        uint4 p;
        p.x = pkrtz(v[0], v[1]); p.y = pkrtz(v[2], v[3]);
        p.z = w2w; p.w = 0u;
        (isV ? aeV : aeU)[(ts * 4 + t) * 64 + lane] = p;
    } else if (idx < 3072) {                          // fw1: (ts, sp, t2, lane)
        int i2 = idx - 1536;
        int lane = i2 & 63, t2 = (i2 >> 6) & 3, sp = (i2 >> 8) & 1, ts = i2 >> 9;
        int nl = lane & 15, qd = lane >> 4;
        float v[8];
        #pragma unroll
        for (int j = 0; j < 8; ++j) {
            int k = (2 * (j >> 2) + sp) * 16 + qd * 4 + (j & 3);   // sigma-permuted k
            v[j] = W1[ts * 64 * 64 + k * 64 + t2 * 16 + nl];
        }
        uint4 p;
        p.x = pkrtz(v[0], v[1]); p.y = pkrtz(v[2], v[3]);
        p.z = pkrtz(v[4], v[5]); p.w = pkrtz(v[6], v[7]);
        fw1[(ts * 8 + sp * 4 + t2) * 64 + lane] = p;
    } else if (idx < 3264) {                          // b1s / w2s
        int i2 = idx - 3072;
        b1s[i2] = b1[i2] * 0.0625f;
        w2s[i2] = W2[i2] * 16.f;
    } else if (idx < 3520) {                          // q -> qout
        int i4 = idx - 3264;
        *(float4*)&qout[i4 * 4] = *(const float4*)&qin[i4 * 4];
    } else if (idx < 5056) {                          // fw0a / fw0b
        int i2 = idx - 3520;                          // 0..1535
        int isB = (i2 >= 768);
        if (isB) i2 -= 768;
        int lane = i2 & 63, t = (i2 >> 6) & 3, ts = i2 >> 8;
        int nl = lane & 15, qd = lane >> 4;
        int rbase = isB ? 32 : 0;
        float v[8];
        #pragma unroll
        for (int j = 0; j < 8; ++j)
            v[j] = W0[ts * 80 * 64 + (rbase + qd * 8 + j) * 64 + t * 16 + nl] * 0.0625f;
        uint4 p;
        p.x = pkrtz(v[0], v[1]); p.y = pkrtz(v[2], v[3]);
        p.z = pkrtz(v[4], v[5]); p.w = pkrtz(v[6], v[7]);
        (isB ? fw0b : fw0a)[(ts * 4 + t) * 64 + lane] = p;
    }
}

// --- per-timestep projection: P,Q (fp32, +b0, /16) + aH (h only, f16) + q snapshot ---
__global__ __launch_bounds__(256) void epn_proj_kernel(
    const float* __restrict__ h, const float* __restrict__ qcur,
    const float* __restrict__ W0, const float* __restrict__ b0,
    float* __restrict__ P, float* __restrict__ Q,
    _Float16* __restrict__ aH, float* __restrict__ qsn)
{
    __shared__ float sa[4][32];
    const int tid = threadIdx.x;
    const int base = blockIdx.x * 4;
    if (tid < 128) {
        int la = tid >> 5, c = tid & 31, atom = base + la;
        sa[la][c] = (c < 31) ? h[atom * 31 + c] : qcur[atom];
    }
    __syncthreads();
    if (tid < 128) {   // h snapshot only; q slot zeroed (f16 range!)
        int la = tid >> 5, c = tid & 31;
        aH[(base + la) * 32 + c] = (c < 31) ? (_Float16)sa[la][c] : (_Float16)0.f;
    }
    if (tid < 4) qsn[base + tid] = sa[tid][31];   // fp32 q snapshot
    const int la = tid >> 6, m = tid & 63, atom = base + la;
    float accP = b0[m], accQ = b0[m];             // b0 in BOTH: each is a C-init
    #pragma unroll
    for (int c = 0; c < 32; ++c) {
        float av = sa[la][c];
        accP = fmaf(av, W0[c * 64 + m], accP);
        accQ = fmaf(av, W0[(32 + c) * 64 + m], accQ);
    }
    P[atom * 64 + m] = accP * 0.0625f;
    Q[atom * 64 + m] = accQ * 0.0625f;
}

// ---------------- main pair kernel: grid dim3(16, 64) ----------------
__global__ __launch_bounds__(256, 4) void epn_main_kernel(
    const float* __restrict__ e, const float* __restrict__ mask,
    const float* __restrict__ Pg, const float* __restrict__ Qg,
    const _Float16* __restrict__ aH, const float* __restrict__ qsn,
    const uint4* __restrict__ aeUg,      // [4][64]
    const uint4* __restrict__ aeVg,      // [4][64]
    const uint4* __restrict__ fragW0a,   // [4][64]
    const uint4* __restrict__ fragW0b,   // [4][64]
    const uint4* __restrict__ fragW1,    // [8][64] (sp*4+t2 major)
    const float* __restrict__ b1s, const float* __restrict__ w2s,
    float* __restrict__ qout)
{
    __shared__ float sPi[16][64], sQi[16][64];   // i-side C-inits (broadcast reads)
    __shared__ _Float16 sa[64][40];              // h_j f16, stride 40 (16B-aligned, 2-way banks)
    __shared__ float sb1[64], sw2[64], sqj[64];

    const int tid  = threadIdx.x;
    const int lane = tid & 63;
    const int wv   = tid >> 6;
    const int nl   = lane & 15;
    const int qd   = lane >> 4;
    const int i0   = blockIdx.y * 16;    // 64 i-tiles
    const int jb   = blockIdx.x * 64;    // 16 j-blocks, each walks 4 j-tiles

    // stage everything ONCE (no per-step restaging, no loop barriers)
    const int sr = tid >> 4, sc4 = (tid & 15) * 4;
    *(float4*)&sPi[sr][sc4] = *(const float4*)&Pg[(i0 + sr) * 64 + sc4];
    *(float4*)&sQi[sr][sc4] = *(const float4*)&Qg[(i0 + sr) * 64 + sc4];
    {
        const int atom = tid >> 2, seg = (tid & 3) * 8;
        *(uint4*)&sa[atom][seg] = *(const uint4*)&aH[(jb + atom) * 32 + seg];
    }
    if (tid < 64) {
        sb1[tid] = b1s[tid]; sw2[tid] = w2s[tid]; sqj[tid] = qsn[jb + tid];
    }

    // weight frags in registers
    uint4 aeu[4], aev[4], Aw0a[4], Aw0b[4], w1r[8];
    #pragma unroll
    for (int t = 0; t < 4; ++t) {
        aeu[t]  = aeUg[t * 64 + lane];
        aev[t]  = aeVg[t * 64 + lane];
        Aw0a[t] = fragW0a[t * 64 + lane];
        Aw0b[t] = fragW0b[t * 64 + lane];
    }
    #pragma unroll
    for (int i = 0; i < 8; ++i) w1r[i] = fragW1[i * 64 + lane];

    // e/mask prefetch for gs=0
    float4 eP = *(const float4*)(e + ((size_t)(i0 + wv * 4) * Nn + (jb + nl)) * 16 + qd * 4);
    float  mP = mask[(size_t)(i0 + wv * 4) * Nn + jb + nl];

    float sacc[4] = {0.f, 0.f, 0.f, 0.f};

    __syncthreads();

    #pragma unroll
    for (int st = 0; st < 4; ++st) {
        // B-frag of h_j for this j-tile: B[k=qd*8+j, n=nl]
        const half8 BaH = *(const half8*)&sa[st * 16 + nl][qd * 8];
        // q_j hi/lo pair for the widened e-term (slots k: elem4=hi, elem5=lo, qd==0 only)
        const float qv  = sqj[st * 16 + nl];
        const float qh  = (float)(_Float16)(qv * 0.0625f);
        const float qlo = fmaf(qh, -16.f, qv);
        const unsigned int qpk = (qd == 0) ? pk_rtn(qh, qlo) : 0u;

        #pragma unroll
        for (int g = 0; g < 4; ++g) {
            const int il = wv * 4 + g;
            float4 ec = eP; float mc = mP;
            const int gs = st * 4 + g;
            if (gs < 15) {   // prefetch next (step, group)
                int ngs = gs + 1, nst = ngs >> 2, ng = ngs & 3;
                int nil = wv * 4 + ng;
                eP = *(const float4*)(e + ((size_t)(i0 + nil) * Nn + (jb + nst * 16 + nl)) * 16 + qd * 4);
                mP = mask[(size_t)(i0 + nil) * Nn + jb + nst * 16 + nl];
            }

            uint4v bfe;
            bfe[0] = pkrtz(ec.x, ec.y);
            bfe[1] = pkrtz(ec.z, ec.w);
            bfe[2] = qpk;
            bfe[3] = 0u;
            half8 Be = __builtin_bit_cast(half8, bfe);

            // layer 1: h_j-term via K=32 MFMA (C = Pi or Qi), then e+q-term K=32
            uint4v bu[2], bv[2];
            #pragma unroll
            for (int t = 0; t < 4; ++t) {
                const int off = t * 16 + qd * 4;
                f32x4 Ci = *(const f32x4*)&sPi[il][off];    // broadcast
                f32x4 Cq = *(const f32x4*)&sQi[il][off];
                f32x4 Eu = MFMAH32(__builtin_bit_cast(half8, aeu[t]), Be,
                           MFMAH32(__builtin_bit_cast(half8, Aw0b[t]), BaH, Ci));
                f32x4 Ev = MFMAH32(__builtin_bit_cast(half8, aev[t]), Be,
                           MFMAH32(__builtin_bit_cast(half8, Aw0a[t]), BaH, Cq));
                const int sp = t & 1, b = (t >> 1) * 2;
                bu[sp][b]     = relu_pk(pkrtz(Eu[0], Eu[1]));
                bu[sp][b + 1] = relu_pk(pkrtz(Eu[2], Eu[3]));
                bv[sp][b]     = relu_pk(pkrtz(Ev[0], Ev[1]));
                bv[sp][b + 1] = relu_pk(pkrtz(Ev[2], Ev[3]));
            }

            // layer 2 (C-init = b1/16) + epilogue (16x folded into w2s)
            f32x4 s4 = {0.f, 0.f, 0.f, 0.f};
            #pragma unroll
            for (int t2 = 0; t2 < 4; ++t2) {
                f32x4 binit = *(const f32x4*)&sb1[t2 * 16 + qd * 4];
                f32x4 w2q   = *(const f32x4*)&sw2[t2 * 16 + qd * 4];
                half8 w1a = __builtin_bit_cast(half8, w1r[t2]);
                half8 w1b = __builtin_bit_cast(half8, w1r[4 + t2]);
                f32x4 x = MFMAH32(w1a, __builtin_bit_cast(half8, bu[0]), binit);
                x = MFMAH32(w1b, __builtin_bit_cast(half8, bu[1]), x);
                f32x4 y = MFMAH32(w1a, __builtin_bit_cast(half8, bv[0]), binit);
                y = MFMAH32(w1b, __builtin_bit_cast(half8, bv[1]), y);
                s4 += (max0(x) - max0(y)) * w2q;
            }

            sacc[g] += ((s4[0] + s4[1]) + (s4[2] + s4[3])) * mc;
        }
    }

    // one reduction + atomic per i-atom (was one per i per j-step)
    #pragma unroll
    for (int g = 0; g < 4; ++g) {
        float s = sacc[g];
        s += __shfl_xor(s, 1);
        s += __shfl_xor(s, 2);
        s += __shfl_xor(s, 4);
        s += __shfl_xor(s, 8);
        s += __shfl_xor(s, 16);
        s += __shfl_xor(s, 32);
        if (lane == 0) atomicAdd(&qout[i0 + wv * 4 + g], s);
    }
}

extern "C" void kernel_launch(void* const* d_in, const int* in_sizes, int n_in,
                              void* d_out, int out_size, void* d_ws, size_t ws_size,
                              hipStream_t stream) {
    const float* h    = (const float*)d_in[0];
    const float* e    = (const float*)d_in[1];
    const float* q    = (const float*)d_in[2];
    const float* mask = (const float*)d_in[3];
    const float* W0   = (const float*)d_in[5];
    const float* b0   = (const float*)d_in[6];
    const float* W1   = (const float*)d_in[7];
    const float* b1   = (const float*)d_in[8];
    const float* W2   = (const float*)d_in[9];
    // d_in[10] = b2 cancels in the antisymmetrization

    float* qout = (float*)d_out;
    char*  ws   = (char*)d_ws;
    float*    Pws  = (float*)(ws);                           // 256 KB
    float*    Qws  = (float*)(ws + 256 * 1024);              // 256 KB
    _Float16* aH   = (_Float16*)(ws + 512 * 1024);           // 64 KB
    float*    qsn  = (float*)(ws + 576 * 1024);              // 4 KB
    char*     fb   = ws + 580 * 1024;
    uint4*    aeU  = (uint4*)(fb);                           // 12 KB
    uint4*    aeV  = (uint4*)(fb + 12288);                   // 12 KB
    uint4*    fw0a = (uint4*)(fb + 24576);                   // 12 KB
    uint4*    fw0b = (uint4*)(fb + 36864);                   // 12 KB
    uint4*    fw1  = (uint4*)(fb + 49152);                   // 24 KB
    float*    b1s  = (float*)(fb + 73728);                   // 768 B
    float*    w2s  = (float*)(fb + 74496);                   // 768 B

    epn_frag_kernel<<<20, 256, 0, stream>>>(W0, W1, b1, W2, q,
                                            aeU, aeV, fw0a, fw0b, fw1, b1s, w2s, qout);
    for (int t = 0; t < 3; ++t) {
        epn_proj_kernel<<<256, 256, 0, stream>>>(h, qout, W0 + t * 80 * 64, b0 + t * 64,
                                                 Pws, Qws, aH, qsn);
        epn_main_kernel<<<dim3(16, 64), 256, 0, stream>>>(
            e, mask, Pws, Qws, aH, qsn,
            aeU + (size_t)t * 4 * 64, aeV + (size_t)t * 4 * 64,
            fw0a + (size_t)t * 4 * 64, fw0b + (size_t)t * 4 * 64,
            fw1 + (size_t)t * 8 * 64,
            b1s + t * 64, w2s + t * 64, qout);
    }
}

// Round 3
// 316.835 us; speedup vs baseline: 5.0830x; 5.0830x over previous
//
#include <hip/hip_runtime.h>

// EPN_flax, round 12: round-11 structure, register diet to kill scratch spill.
// Round-11 failure mode: +56 persistent frag VGPRs vs round 9 against the
// (256,4) 128-reg cap -> hot-loop spill: WRITE_SIZE 2->679 MB, 523 us/dispatch.
// Fixes: (1) aeu/aev merged into ONE A-frag: u-dir q-weights (W0[63] hi/lo) in
// word z (k=4,5), v-dir (W0[31]) in word w (k=6,7); direction selected on the
// B side (Beu={e,e,qpk,0}, Bev={e,e,0,qpk}), built per-iter anyway. -16 VGPRs.
// (2) launch_bounds(256,2) + grid dim3(8,64) = 512 blocks = exactly 2/CU, all
// co-resident, VGPR cap 256 -> allocator has slack (~150 live), zero spill.
// Each block walks 8 j-tiles; st-loop dynamic (I-cache), g-loop unrolled.
// Numerics identical to round 11 (passed, absmax 1024 = round-9 level).

constexpr int Nn = 1024;

typedef _Float16 half8 __attribute__((ext_vector_type(8)));
typedef __fp16   fp16x2 __attribute__((ext_vector_type(2)));
typedef float    f32x4 __attribute__((ext_vector_type(4)));
typedef unsigned int uint4v __attribute__((ext_vector_type(4)));

#define MFMAH32(A, B, C) __builtin_amdgcn_mfma_f32_16x16x32_f16(A, B, C, 0, 0, 0)

__device__ inline unsigned int pkrtz(float a, float b) {
    fp16x2 r = __builtin_amdgcn_cvt_pkrtz(a, b);
    return __builtin_bit_cast(unsigned int, r);
}
__device__ inline f32x4 max0(f32x4 a) {
    f32x4 z = {0.f, 0.f, 0.f, 0.f};
    return __builtin_elementwise_max(a, z);
}
// relu on a packed f16 pair (v_pk_max_f16); pkrtz(neg) stays <=0 so
// relu-after-pack == pack-after-relu.
__device__ inline unsigned int relu_pk(unsigned int u) {
    fp16x2 h = __builtin_bit_cast(fp16x2, u);
    fp16x2 z = {(__fp16)0.f, (__fp16)0.f};
    h = __builtin_elementwise_max(h, z);
    return __builtin_bit_cast(unsigned int, h);
}
__device__ inline unsigned int pk_rtn(float lo, float hi) {
    unsigned short l = __builtin_bit_cast(unsigned short, (_Float16)lo);
    unsigned short h = __builtin_bit_cast(unsigned short, (_Float16)hi);
    return ((unsigned int)h << 16) | (unsigned int)l;
}

// ---- setup: weight fragments (3 timesteps), scaled b1/W2, q->qout copy ----
__global__ __launch_bounds__(256) void epn_frag_kernel(
    const float* __restrict__ W0,   // [3][80][64]
    const float* __restrict__ W1,   // [3][64][64]
    const float* __restrict__ b1,   // [3][64]
    const float* __restrict__ W2,   // [3][64]
    const float* __restrict__ qin,
    uint4* __restrict__ ae,         // [3][4][64]  K=32 e-term A-frags (z=u-q, w=v-q wts)
    uint4* __restrict__ fw0a,       // [3][4][64]  K=32 A-frags (W0 rows 0..31, /16)
    uint4* __restrict__ fw0b,       // [3][4][64]  K=32 A-frags (W0 rows 32..63, /16)
    uint4* __restrict__ fw1,        // [3][8][64]  sigma-permuted K=32 A-frags
    float* __restrict__ b1s,        // [3][64] = b1/16
    float* __restrict__ w2s,        // [3][64] = 16*W2
    float* __restrict__ qout)
{
    const int idx = blockIdx.x * 256 + threadIdx.x;   // grid 17 -> 4352
    if (idx < 768) {                                  // ae: (ts, t, lane)
        int lane = idx & 63, t = (idx >> 6) & 3, ts = idx >> 8;
        int nl = lane & 15, qd = lane >> 4;
        float v[4];
        #pragma unroll
        for (int j = 0; j < 4; ++j)
            v[j] = W0[ts * 80 * 64 + (64 + qd * 4 + j) * 64 + t * 16 + nl] * 0.0625f;
        unsigned int wzu = 0u, wzv = 0u;
        if (qd == 0) {   // q slots: lo-elem pairs f16(q/16), hi-elem pairs residual
            float wqu = W0[ts * 80 * 64 + 63 * 64 + t * 16 + nl];
            float wqv = W0[ts * 80 * 64 + 31 * 64 + t * 16 + nl];
            wzu = pk_rtn(wqu, wqu * 0.0625f);
            wzv = pk_rtn(wqv, wqv * 0.0625f);
        }
        uint4 p;
        p.x = pkrtz(v[0], v[1]); p.y = pkrtz(v[2], v[3]);
        p.z = wzu; p.w = wzv;
        ae[idx] = p;
    } else if (idx < 2304) {                          // fw1: (ts, sp, t2, lane)
        int i2 = idx - 768;
        int lane = i2 & 63, t2 = (i2 >> 6) & 3, sp = (i2 >> 8) & 1, ts = i2 >> 9;
        int nl = lane & 15, qd = lane >> 4;
        float v[8];
        #pragma unroll
        for (int j = 0; j < 8; ++j) {
            int k = (2 * (j >> 2) + sp) * 16 + qd * 4 + (j & 3);   // sigma-permuted k
            v[j] = W1[ts * 64 * 64 + k * 64 + t2 * 16 + nl];
        }
        uint4 p;
        p.x = pkrtz(v[0], v[1]); p.y = pkrtz(v[2], v[3]);
        p.z = pkrtz(v[4], v[5]); p.w = pkrtz(v[6], v[7]);
        fw1[(ts * 8 + sp * 4 + t2) * 64 + lane] = p;
    } else if (idx < 2496) {                          // b1s / w2s
        int i2 = idx - 2304;
        b1s[i2] = b1[i2] * 0.0625f;
        w2s[i2] = W2[i2] * 16.f;
    } else if (idx < 2752) {                          // q -> qout
        int i4 = idx - 2496;
        *(float4*)&qout[i4 * 4] = *(const float4*)&qin[i4 * 4];
    } else if (idx < 4288) {                          // fw0a / fw0b
        int i2 = idx - 2752;                          // 0..1535
        int isB = (i2 >= 768);
        if (isB) i2 -= 768;
        int lane = i2 & 63, t = (i2 >> 6) & 3, ts = i2 >> 8;
        int nl = lane & 15, qd = lane >> 4;
        int rbase = isB ? 32 : 0;
        float v[8];
        #pragma unroll
        for (int j = 0; j < 8; ++j)
            v[j] = W0[ts * 80 * 64 + (rbase + qd * 8 + j) * 64 + t * 16 + nl] * 0.0625f;
        uint4 p;
        p.x = pkrtz(v[0], v[1]); p.y = pkrtz(v[2], v[3]);
        p.z = pkrtz(v[4], v[5]); p.w = pkrtz(v[6], v[7]);
        (isB ? fw0b : fw0a)[(ts * 4 + t) * 64 + lane] = p;
    }
}

// --- per-timestep projection: P,Q (fp32, +b0, /16) + aH (h only, f16) + q snapshot ---
__global__ __launch_bounds__(256) void epn_proj_kernel(
    const float* __restrict__ h, const float* __restrict__ qcur,
    const float* __restrict__ W0, const float* __restrict__ b0,
    float* __restrict__ P, float* __restrict__ Q,
    _Float16* __restrict__ aH, float* __restrict__ qsn)
{
    __shared__ float sa[4][32];
    const int tid = threadIdx.x;
    const int base = blockIdx.x * 4;
    if (tid < 128) {
        int la = tid >> 5, c = tid & 31, atom = base + la;
        sa[la][c] = (c < 31) ? h[atom * 31 + c] : qcur[atom];
    }
    __syncthreads();
    if (tid < 128) {   // h snapshot only; q slot zeroed (f16 range!)
        int la = tid >> 5, c = tid & 31;
        aH[(base + la) * 32 + c] = (c < 31) ? (_Float16)sa[la][c] : (_Float16)0.f;
    }
    if (tid < 4) qsn[base + tid] = sa[tid][31];   // fp32 q snapshot
    const int la = tid >> 6, m = tid & 63, atom = base + la;
    float accP = b0[m], accQ = b0[m];             // b0 in BOTH: each is a C-init
    #pragma unroll
    for (int c = 0; c < 32; ++c) {
        float av = sa[la][c];
        accP = fmaf(av, W0[c * 64 + m], accP);
        accQ = fmaf(av, W0[(32 + c) * 64 + m], accQ);
    }
    P[atom * 64 + m] = accP * 0.0625f;
    Q[atom * 64 + m] = accQ * 0.0625f;
}

// ---------------- main pair kernel: grid dim3(8, 64), 2 blocks/CU ----------------
__global__ __launch_bounds__(256, 2) void epn_main_kernel(
    const float* __restrict__ e, const float* __restrict__ mask,
    const float* __restrict__ Pg, const float* __restrict__ Qg,
    const _Float16* __restrict__ aH, const float* __restrict__ qsn,
    const uint4* __restrict__ aeg,       // [4][64]
    const uint4* __restrict__ fragW0a,   // [4][64]
    const uint4* __restrict__ fragW0b,   // [4][64]
    const uint4* __restrict__ fragW1,    // [8][64] (sp*4+t2 major)
    const float* __restrict__ b1s, const float* __restrict__ w2s,
    float* __restrict__ qout)
{
    __shared__ float sPi[16][64], sQi[16][64];   // i-side C-inits (broadcast reads)
    __shared__ _Float16 sa[128][40];             // h_j f16, stride 40 (16B-aligned)
    __shared__ float sb1[64], sw2[64], sqj[128];

    const int tid  = threadIdx.x;
    const int lane = tid & 63;
    const int wv   = tid >> 6;
    const int nl   = lane & 15;
    const int qd   = lane >> 4;
    const int i0   = blockIdx.y * 16;    // 64 i-tiles
    const int jb   = blockIdx.x * 128;   // 8 j-blocks, each walks 8 j-tiles

    // stage everything ONCE (no per-step restaging, no loop barriers)
    const int sr = tid >> 4, sc4 = (tid & 15) * 4;
    *(float4*)&sPi[sr][sc4] = *(const float4*)&Pg[(i0 + sr) * 64 + sc4];
    *(float4*)&sQi[sr][sc4] = *(const float4*)&Qg[(i0 + sr) * 64 + sc4];
    #pragma unroll
    for (int r = 0; r < 2; ++r) {
        const int idx = tid + r * 256;            // 512 uint4 = 128 atoms x 64B
        const int atom = idx >> 2, seg = (idx & 3) * 8;
        *(uint4*)&sa[atom][seg] = *(const uint4*)&aH[(jb + atom) * 32 + seg];
    }
    if (tid < 128) sqj[tid] = qsn[jb + tid];
    if (tid < 64) { sb1[tid] = b1s[tid]; sw2[tid] = w2s[tid]; }

    // weight frags in registers (~80 VGPRs persistent)
    uint4 aef[4], Aw0a[4], Aw0b[4], w1r[8];
    #pragma unroll
    for (int t = 0; t < 4; ++t) {
        aef[t]  = aeg[t * 64 + lane];
        Aw0a[t] = fragW0a[t * 64 + lane];
        Aw0b[t] = fragW0b[t * 64 + lane];
    }
    #pragma unroll
    for (int i = 0; i < 8; ++i) w1r[i] = fragW1[i * 64 + lane];

    // e/mask prefetch for (st=0, g=0)
    float4 eP = *(const float4*)(e + ((size_t)(i0 + wv * 4) * Nn + (jb + nl)) * 16 + qd * 4);
    float  mP = mask[(size_t)(i0 + wv * 4) * Nn + jb + nl];

    float sacc[4] = {0.f, 0.f, 0.f, 0.f};

    __syncthreads();

    for (int st = 0; st < 8; ++st) {   // dynamic: keeps body ~5 KB of I-cache
        // B-frag of h_j for this j-tile: B[k=qd*8+j, n=nl]
        const half8 BaH = *(const half8*)&sa[st * 16 + nl][qd * 8];
        // q_j hi/lo pair (k=4,5 for u-dir / k=6,7 for v-dir on the B side)
        const float qv  = sqj[st * 16 + nl];
        const float qh  = (float)(_Float16)(qv * 0.0625f);
        const float qlo = fmaf(qh, -16.f, qv);
        const unsigned int qpk = pk_rtn(qh, qlo);

        #pragma unroll
        for (int g = 0; g < 4; ++g) {
            const int il = wv * 4 + g;
            float4 ec = eP; float mc = mP;
            // prefetch next (st, g)
            if (g < 3) {
                eP = *(const float4*)(e + ((size_t)(i0 + il + 1) * Nn + (jb + st * 16 + nl)) * 16 + qd * 4);
                mP = mask[(size_t)(i0 + il + 1) * Nn + jb + st * 16 + nl];
            } else if (st < 7) {
                eP = *(const float4*)(e + ((size_t)(i0 + wv * 4) * Nn + (jb + (st + 1) * 16 + nl)) * 16 + qd * 4);
                mP = mask[(size_t)(i0 + wv * 4) * Nn + jb + (st + 1) * 16 + nl];
            }

            const unsigned int pk01 = pkrtz(ec.x, ec.y);
            const unsigned int pk23 = pkrtz(ec.z, ec.w);
            uint4v beu = {pk01, pk23, qpk, 0u};   // u-dir: q hits A word z (k=4,5)
            uint4v bev = {pk01, pk23, 0u, qpk};   // v-dir: q hits A word w (k=6,7)
            half8 Beu = __builtin_bit_cast(half8, beu);
            half8 Bev = __builtin_bit_cast(half8, bev);

            // layer 1: h_j-term via K=32 MFMA (C = Pi or Qi), then e+q-term K=32
            uint4v bu[2], bv[2];
            #pragma unroll
            for (int t = 0; t < 4; ++t) {
                const int off = t * 16 + qd * 4;
                f32x4 Ci = *(const f32x4*)&sPi[il][off];    // broadcast
                f32x4 Cq = *(const f32x4*)&sQi[il][off];
                half8 aw = __builtin_bit_cast(half8, aef[t]);
                f32x4 Eu = MFMAH32(aw, Beu,
                           MFMAH32(__builtin_bit_cast(half8, Aw0b[t]), BaH, Ci));
                f32x4 Ev = MFMAH32(aw, Bev,
                           MFMAH32(__builtin_bit_cast(half8, Aw0a[t]), BaH, Cq));
                const int sp = t & 1, b = (t >> 1) * 2;
                bu[sp][b]     = relu_pk(pkrtz(Eu[0], Eu[1]));
                bu[sp][b + 1] = relu_pk(pkrtz(Eu[2], Eu[3]));
                bv[sp][b]     = relu_pk(pkrtz(Ev[0], Ev[1]));
                bv[sp][b + 1] = relu_pk(pkrtz(Ev[2], Ev[3]));
            }

            // layer 2 (C-init = b1/16) + epilogue (16x folded into w2s)
            f32x4 s4 = {0.f, 0.f, 0.f, 0.f};
            #pragma unroll
            for (int t2 = 0; t2 < 4; ++t2) {
                f32x4 binit = *(const f32x4*)&sb1[t2 * 16 + qd * 4];
                f32x4 w2q   = *(const f32x4*)&sw2[t2 * 16 + qd * 4];
                half8 w1a = __builtin_bit_cast(half8, w1r[t2]);
                half8 w1b = __builtin_bit_cast(half8, w1r[4 + t2]);
                f32x4 x = MFMAH32(w1a, __builtin_bit_cast(half8, bu[0]), binit);
                x = MFMAH32(w1b, __builtin_bit_cast(half8, bu[1]), x);
                f32x4 y = MFMAH32(w1a, __builtin_bit_cast(half8, bv[0]), binit);
                y = MFMAH32(w1b, __builtin_bit_cast(half8, bv[1]), y);
                s4 += (max0(x) - max0(y)) * w2q;
            }

            sacc[g] += ((s4[0] + s4[1]) + (s4[2] + s4[3])) * mc;
        }
    }

    // one reduction + atomic per i-atom (8 j-tiles folded in registers)
    #pragma unroll
    for (int g = 0; g < 4; ++g) {
        float s = sacc[g];
        s += __shfl_xor(s, 1);
        s += __shfl_xor(s, 2);
        s += __shfl_xor(s, 4);
        s += __shfl_xor(s, 8);
        s += __shfl_xor(s, 16);
        s += __shfl_xor(s, 32);
        if (lane == 0) atomicAdd(&qout[i0 + wv * 4 + g], s);
    }
}

extern "C" void kernel_launch(void* const* d_in, const int* in_sizes, int n_in,
                              void* d_out, int out_size, void* d_ws, size_t ws_size,
                              hipStream_t stream) {
    const float* h    = (const float*)d_in[0];
    const float* e    = (const float*)d_in[1];
    const float* q    = (const float*)d_in[2];
    const float* mask = (const float*)d_in[3];
    const float* W0   = (const float*)d_in[5];
    const float* b0   = (const float*)d_in[6];
    const float* W1   = (const float*)d_in[7];
    const float* b1   = (const float*)d_in[8];
    const float* W2   = (const float*)d_in[9];
    // d_in[10] = b2 cancels in the antisymmetrization

    float* qout = (float*)d_out;
    char*  ws   = (char*)d_ws;
    float*    Pws  = (float*)(ws);                           // 256 KB
    float*    Qws  = (float*)(ws + 256 * 1024);              // 256 KB
    _Float16* aH   = (_Float16*)(ws + 512 * 1024);           // 64 KB
    float*    qsn  = (float*)(ws + 576 * 1024);              // 4 KB
    char*     fb   = ws + 580 * 1024;
    uint4*    ae   = (uint4*)(fb);                           // 12 KB
    uint4*    fw0a = (uint4*)(fb + 12288);                   // 12 KB
    uint4*    fw0b = (uint4*)(fb + 24576);                   // 12 KB
    uint4*    fw1  = (uint4*)(fb + 36864);                   // 24 KB
    float*    b1s  = (float*)(fb + 61440);                   // 768 B
    float*    w2s  = (float*)(fb + 62208);                   // 768 B

    epn_frag_kernel<<<17, 256, 0, stream>>>(W0, W1, b1, W2, q,
                                            ae, fw0a, fw0b, fw1, b1s, w2s, qout);
    for (int t = 0; t < 3; ++t) {
        epn_proj_kernel<<<256, 256, 0, stream>>>(h, qout, W0 + t * 80 * 64, b0 + t * 64,
                                                 Pws, Qws, aH, qsn);
        epn_main_kernel<<<dim3(8, 64), 256, 0, stream>>>(
            e, mask, Pws, Qws, aH, qsn,
            ae + (size_t)t * 4 * 64,
            fw0a + (size_t)t * 4 * 64, fw0b + (size_t)t * 4 * 64,
            fw1 + (size_t)t * 8 * 64,
            b1s + t * 64, w2s + t * 64, qout);
    }
}